// Round 7
// baseline (1384.227 us; speedup 1.0000x reference)
//
#include <hip/hip_runtime.h>
#include <math.h>

#define NLAYERS 4
#define H 4
#define C 64
#define D 64
#define HC 256     // H*C
#define D3 192     // 3*D
#define NEG 0.2f

typedef float f32x4 __attribute__((ext_vector_type(4)));
typedef short bf16x8 __attribute__((ext_vector_type(8)));
typedef unsigned short u16;

// fp32 -> bf16 round-to-nearest-even
__device__ __forceinline__ u16 f2bf(float f) {
    unsigned u = __float_as_uint(f);
    u += 0x7FFFu + ((u >> 16) & 1u);
    return (u16)(u >> 16);
}
__device__ __forceinline__ float bf2f(u16 h) {
    return __uint_as_float((unsigned)h << 16);
}

// ---- K0: per-layer small weight folds. One block PER LAYER (4 blocks, one launch). ----
__global__ void k_weffs(const float* __restrict__ W_edge, const float* __restrict__ att_edge,
                        const float* __restrict__ W_lin, const float* __restrict__ att_s,
                        const float* __restrict__ att_d,
                        float* __restrict__ weff, float* __restrict__ w_asd) {
    int l = blockIdx.x;
    const float* We = W_edge + (size_t)l * D * HC;
    const float* Wl = W_lin + (size_t)l * D * HC;
    const float* ae = att_edge + l * H * C;
    const float* as_ = att_s + l * H * C;
    const float* ad = att_d + l * H * C;
    int t = threadIdx.x;
    int d = t >> 2, h = t & 3;
    float se = 0.f, ss = 0.f, sd = 0.f;
    #pragma unroll
    for (int c = 0; c < C; ++c) {
        float we = We[d * HC + h * C + c];
        float wl = Wl[d * HC + h * C + c];
        se = fmaf(we, ae[h * C + c], se);
        ss = fmaf(wl, as_[h * C + c], ss);
        sd = fmaf(wl, ad[h * C + c], sd);
    }
    weff[l * HC + d * 4 + h] = se;
    w_asd[l * 512 + d * 8 + h] = ss;
    w_asd[l * 512 + d * 8 + 4 + h] = sd;
}

// ---- K0b: convert W1 -> W1^T bf16, W2 -> W2^T bf16 ----
__global__ void k_cvtw(const float* __restrict__ W1, const float* __restrict__ W2,
                       u16* __restrict__ W1T, u16* __restrict__ W2T) {
    int i = blockIdx.x * 256 + threadIdx.x;
    if (i < NLAYERS * D3 * D3) {
        int l = i / (D3 * D3), r = i % (D3 * D3);
        int n = r / D3, k = r % D3;
        W1T[i] = f2bf(W1[l * D3 * D3 + k * D3 + n]);
    } else {
        int j = i - NLAYERS * D3 * D3;
        if (j < NLAYERS * D3 * D) {
            int l = j / (D3 * D), r = j % (D3 * D);
            int n = r / D3, k = r % D3;
            W2T[j] = f2bf(W2[l * D3 * D + k * D + n]);
        }
    }
}

// ---- K0c: W_lin -> transposed split-bf16 (hi + residual-lo). WLT[l][o][d]. ----
__global__ void k_cvtwl(const float* __restrict__ W_lin,
                        u16* __restrict__ WTh, u16* __restrict__ WTl) {
    int i = blockIdx.x * 256 + threadIdx.x;
    if (i >= NLAYERS * HC * D) return;
    int l = i / (HC * D), r = i % (HC * D);
    int o = r / D, d = r % D;
    float v = W_lin[(size_t)l * D * HC + d * HC + o];
    u16 h = f2bf(v);
    WTh[i] = h;
    WTl[i] = f2bf(v - bf2f(h));
}

// ---- CSR build (once per launch) ----
__global__ void k_hist(const int* __restrict__ dst, int* __restrict__ deg, int E) {
    int i = blockIdx.x * blockDim.x + threadIdx.x;
    if (i < E) atomicAdd(&deg[dst[i]], 1);
}

__global__ void k_scan(const int* __restrict__ deg, int* __restrict__ rowptr,
                       int* __restrict__ head, int N, int E) {
    __shared__ int lds[1024];
    int t = threadIdx.x;
    int chunk = (N + 1023) / 1024;
    int begin = t * chunk, end = min(begin + chunk, N);
    int sum = 0;
    for (int i = begin; i < end; ++i) sum += deg[i];
    lds[t] = sum;
    __syncthreads();
    for (int off = 1; off < 1024; off <<= 1) {
        int v = (t >= off) ? lds[t - off] : 0;
        __syncthreads();
        lds[t] += v;
        __syncthreads();
    }
    int running = (t == 0) ? 0 : lds[t - 1];
    for (int i = begin; i < end; ++i) {
        int dg = deg[i];          // read BEFORE head[i] overwrite (deg aliases head)
        rowptr[i] = running;
        head[i] = running;
        running += dg;
    }
    if (t == 0) rowptr[N] = E;
}

__global__ void k_scatter(const int* __restrict__ src, const int* __restrict__ dst,
                          int* __restrict__ head, int* __restrict__ csrpos,
                          int* __restrict__ perm_src, int E) {
    int i = blockIdx.x * blockDim.x + threadIdx.x;
    if (i < E) {
        int d = dst[i];
        int pos = atomicAdd(&head[d], 1);
        csrpos[i] = pos;
        perm_src[pos] = src[i];
    }
}

// ---- K1 (MFMA): x = nf @ W_lin via split-bf16 (fp32-equivalent accuracy). ----
__global__ __launch_bounds__(256, 4) void k_nodeproj_mfma(
    const float* __restrict__ nf, const u16* __restrict__ WTh, const u16* __restrict__ WTl,
    const float* __restrict__ w_asd, float* __restrict__ x,
    float* __restrict__ a_src, float* __restrict__ a_dst, int N, int relu_in) {
    __shared__ __align__(16) u16 s_ah[32 * 72];    // bf16 hi tile, pad 72 (2-way bank max)
    __shared__ __align__(16) u16 s_al[32 * 72];    // bf16 residual tile
    __shared__ __align__(16) float s_nf[32][68];   // fp32 tile for attention dots
    __shared__ __align__(16) float s_wasd[512];
    int tid = threadIdx.x;
    int w = tid >> 6, lane = tid & 63;
    int n0 = blockIdx.x << 5;

    if (tid < 128) *(float4*)&s_wasd[tid * 4] = *(const float4*)&w_asd[tid * 4];

    // stage: thread -> (row = tid>>3, 8 cols at (tid&7)*8). Coalesced 256B per row.
    {
        int r = tid >> 3, c0 = (tid & 7) << 3;
        int n = n0 + r;
        float4 v0 = make_float4(0.f, 0.f, 0.f, 0.f), v1 = v0;
        if (n < N) {
            v0 = *(const float4*)&nf[(size_t)n * D + c0];
            v1 = *(const float4*)&nf[(size_t)n * D + c0 + 4];
        }
        if (relu_in) {
            v0.x = fmaxf(v0.x, 0.f); v0.y = fmaxf(v0.y, 0.f);
            v0.z = fmaxf(v0.z, 0.f); v0.w = fmaxf(v0.w, 0.f);
            v1.x = fmaxf(v1.x, 0.f); v1.y = fmaxf(v1.y, 0.f);
            v1.z = fmaxf(v1.z, 0.f); v1.w = fmaxf(v1.w, 0.f);
        }
        *(float4*)&s_nf[r][c0] = v0;
        *(float4*)&s_nf[r][c0 + 4] = v1;
        float vv[8] = {v0.x, v0.y, v0.z, v0.w, v1.x, v1.y, v1.z, v1.w};
        bf16x8 hv, lv;
        #pragma unroll
        for (int j = 0; j < 8; ++j) {
            u16 h = f2bf(vv[j]);
            hv[j] = (short)h;
            lv[j] = (short)f2bf(vv[j] - bf2f(h));
        }
        *(bf16x8*)&s_ah[r * 72 + c0] = hv;
        *(bf16x8*)&s_al[r * 72 + c0] = lv;
    }
    __syncthreads();

    int m16 = lane & 15, quad = lane >> 4, kq = quad * 8;
    f32x4 acc[2][4];
    #pragma unroll
    for (int mt = 0; mt < 2; ++mt)
        #pragma unroll
        for (int nt = 0; nt < 4; ++nt) {
            acc[mt][nt][0] = 0.f; acc[mt][nt][1] = 0.f;
            acc[mt][nt][2] = 0.f; acc[mt][nt][3] = 0.f;
        }
    #pragma unroll
    for (int ks = 0; ks < 2; ++ks) {
        int ko = ks * 32 + kq;
        bf16x8 ah0 = *(const bf16x8*)&s_ah[m16 * 72 + ko];
        bf16x8 ah1 = *(const bf16x8*)&s_ah[(16 + m16) * 72 + ko];
        bf16x8 al0 = *(const bf16x8*)&s_al[m16 * 72 + ko];
        bf16x8 al1 = *(const bf16x8*)&s_al[(16 + m16) * 72 + ko];
        #pragma unroll
        for (int nt = 0; nt < 4; ++nt) {
            int col = w * 64 + nt * 16 + m16;
            bf16x8 bh = *(const bf16x8*)&WTh[col * D + ko];
            bf16x8 bl = *(const bf16x8*)&WTl[col * D + ko];
            acc[0][nt] = __builtin_amdgcn_mfma_f32_16x16x32_bf16(ah0, bh, acc[0][nt], 0, 0, 0);
            acc[0][nt] = __builtin_amdgcn_mfma_f32_16x16x32_bf16(al0, bh, acc[0][nt], 0, 0, 0);
            acc[0][nt] = __builtin_amdgcn_mfma_f32_16x16x32_bf16(ah0, bl, acc[0][nt], 0, 0, 0);
            acc[1][nt] = __builtin_amdgcn_mfma_f32_16x16x32_bf16(ah1, bh, acc[1][nt], 0, 0, 0);
            acc[1][nt] = __builtin_amdgcn_mfma_f32_16x16x32_bf16(al1, bh, acc[1][nt], 0, 0, 0);
            acc[1][nt] = __builtin_amdgcn_mfma_f32_16x16x32_bf16(ah1, bl, acc[1][nt], 0, 0, 0);
        }
    }
    #pragma unroll
    for (int mt = 0; mt < 2; ++mt) {
        #pragma unroll
        for (int nt = 0; nt < 4; ++nt) {
            int col = w * 64 + nt * 16 + m16;
            #pragma unroll
            for (int r = 0; r < 4; ++r) {
                int n = n0 + mt * 16 + quad * 4 + r;
                if (n < N) x[(size_t)n * HC + col] = acc[mt][nt][r];
            }
        }
    }

    // attention scalars: one (node, o) dot per thread, all 256 active (fp32).
    {
        int nloc = tid >> 3, o = tid & 7;
        float s = 0.f;
        #pragma unroll
        for (int d = 0; d < 64; ++d)
            s = fmaf(s_nf[nloc][d], s_wasd[d * 8 + o], s);
        int n = n0 + nloc;
        if (n < N) {
            if (o < 4) a_src[n * 4 + o] = s;
            else       a_dst[n * 4 + (o - 4)] = s;
        }
    }
}

// ---- K2: per-edge alpha, 16 lanes per edge (4 edges/wave), float4 loads. ----
__global__ void k_alpha(const float* __restrict__ ef, const float* __restrict__ weff,
                        const int* __restrict__ src, const int* __restrict__ dst,
                        const float* __restrict__ a_src, const float* __restrict__ a_dst,
                        const int* __restrict__ csrpos, float* __restrict__ alpha_csr, int E) {
    int wave = (int)((blockIdx.x * blockDim.x + threadIdx.x) >> 6);
    int lane = threadIdx.x & 63;
    int sub = lane >> 4, li = lane & 15;
    int e = wave * 4 + sub;
    if (e >= E) return;
    float4 efv = *(const float4*)&ef[(size_t)e * D + li * 4];
    float4 w0 = *(const float4*)&weff[(li * 4 + 0) * 4];
    float4 w1 = *(const float4*)&weff[(li * 4 + 1) * 4];
    float4 w2 = *(const float4*)&weff[(li * 4 + 2) * 4];
    float4 w3 = *(const float4*)&weff[(li * 4 + 3) * 4];
    float p0 = efv.x * w0.x + efv.y * w1.x + efv.z * w2.x + efv.w * w3.x;
    float p1 = efv.x * w0.y + efv.y * w1.y + efv.z * w2.y + efv.w * w3.y;
    float p2 = efv.x * w0.z + efv.y * w1.z + efv.z * w2.z + efv.w * w3.z;
    float p3 = efv.x * w0.w + efv.y * w1.w + efv.z * w2.w + efv.w * w3.w;
    #pragma unroll
    for (int off = 1; off < 16; off <<= 1) {
        p0 += __shfl_xor(p0, off);
        p1 += __shfl_xor(p1, off);
        p2 += __shfl_xor(p2, off);
        p3 += __shfl_xor(p3, off);
    }
    if (li < 4) {
        float p = (li == 0) ? p0 : (li == 1) ? p1 : (li == 2) ? p2 : p3;
        int s = src[e], dd = dst[e];
        float a = p + a_src[s * 4 + li] + a_dst[dd * 4 + li];
        a = (a > 0.f) ? a : NEG * a;
        alpha_csr[(size_t)csrpos[e] * 4 + li] = a;
    }
}

// ---- K3: fused per-dst GAT. Pass B stores exp() back; pass C 8-deep batched
// issue (load 8 alpha+index, then 32 independent x-gathers in flight). ----
__global__ void k_gat(const float* __restrict__ x, float* __restrict__ alpha_csr,
                      const int* __restrict__ rowptr, const int* __restrict__ perm_src,
                      const float* __restrict__ bias, const float* __restrict__ g,
                      const float* __restrict__ b, float* __restrict__ nf_ln,
                      float* __restrict__ out2, int N) {
    int n = (int)((blockIdx.x * blockDim.x + threadIdx.x) >> 6);
    int lane = threadIdx.x & 63;
    if (n >= N) return;
    int s = rowptr[n], e = rowptr[n + 1];
    int deg = e - s;
    // pass A: per-head max
    float m0 = -1e30f, m1 = -1e30f, m2 = -1e30f, m3 = -1e30f;
    for (int i = lane; i < deg; i += 64) {
        const float4 a = *(const float4*)&alpha_csr[(size_t)(s + i) * 4];
        m0 = fmaxf(m0, a.x); m1 = fmaxf(m1, a.y);
        m2 = fmaxf(m2, a.z); m3 = fmaxf(m3, a.w);
    }
    #pragma unroll
    for (int off = 32; off; off >>= 1) {
        m0 = fmaxf(m0, __shfl_xor(m0, off)); m1 = fmaxf(m1, __shfl_xor(m1, off));
        m2 = fmaxf(m2, __shfl_xor(m2, off)); m3 = fmaxf(m3, __shfl_xor(m3, off));
    }
    // pass B: exp + sum; store exp back (segment exclusive to this wave)
    float d0 = 0.f, d1 = 0.f, d2 = 0.f, d3 = 0.f;
    for (int i = lane; i < deg; i += 64) {
        float4 a = *(const float4*)&alpha_csr[(size_t)(s + i) * 4];
        a.x = expf(a.x - m0); a.y = expf(a.y - m1);
        a.z = expf(a.z - m2); a.w = expf(a.w - m3);
        *(float4*)&alpha_csr[(size_t)(s + i) * 4] = a;
        d0 += a.x; d1 += a.y; d2 += a.z; d3 += a.w;
    }
    #pragma unroll
    for (int off = 32; off; off >>= 1) {
        d0 += __shfl_xor(d0, off); d1 += __shfl_xor(d1, off);
        d2 += __shfl_xor(d2, off); d3 += __shfl_xor(d3, off);
    }
    float i0 = 0.25f / (d0 + 1e-16f), i1 = 0.25f / (d1 + 1e-16f);
    float i2 = 0.25f / (d2 + 1e-16f), i3 = 0.25f / (d3 + 1e-16f);
    // pass C: aggregate, 8 edges batched (issue-all-then-consume), 4 partial accs
    float ac0 = 0.f, ac1 = 0.f, ac2 = 0.f, ac3 = 0.f;
    int j = 0;
    for (; j + 7 < deg; j += 8) {
        float4 av[8];
        int si[8];
        #pragma unroll
        for (int u = 0; u < 8; ++u) {
            av[u] = *(const float4*)&alpha_csr[(size_t)(s + j + u) * 4];
            si[u] = perm_src[s + j + u];
        }
        float t0[8], t1[8], t2[8], t3[8];
        #pragma unroll
        for (int u = 0; u < 8; ++u) {
            const float* xr = x + (size_t)si[u] * HC;
            t0[u] = xr[lane]; t1[u] = xr[64 + lane];
            t2[u] = xr[128 + lane]; t3[u] = xr[192 + lane];
        }
        #pragma unroll
        for (int u = 0; u < 8; ++u) {
            float v = av[u].x * i0 * t0[u] + av[u].y * i1 * t1[u]
                    + av[u].z * i2 * t2[u] + av[u].w * i3 * t3[u];
            if ((u & 3) == 0) ac0 += v;
            else if ((u & 3) == 1) ac1 += v;
            else if ((u & 3) == 2) ac2 += v;
            else ac3 += v;
        }
    }
    for (; j < deg; ++j) {
        const float4 a = *(const float4*)&alpha_csr[(size_t)(s + j) * 4];
        int sidx = perm_src[s + j];
        const float* xr = x + (size_t)sidx * HC;
        ac0 += a.x * i0 * xr[lane] + a.y * i1 * xr[64 + lane]
             + a.z * i2 * xr[128 + lane] + a.w * i3 * xr[192 + lane];
    }
    float acc = (ac0 + ac1) + (ac2 + ac3);
    // bias + LN
    float v = acc + bias[lane];
    float sm = v;
    #pragma unroll
    for (int off = 32; off; off >>= 1) sm += __shfl_xor(sm, off);
    float mu = sm * (1.f / 64.f);
    float dv = v - mu;
    float q = dv * dv;
    #pragma unroll
    for (int off = 32; off; off >>= 1) q += __shfl_xor(q, off);
    float rstd = rsqrtf(q * (1.f / 64.f) + 1e-5f);
    float r = dv * rstd * g[lane] + b[lane];
    nf_ln[(size_t)n * D + lane] = r;
    if (out2) out2[(size_t)n * D + lane] = r;
}

// ---- K6: fused edge MLP, bf16 MFMA, 64 edges/block. Residual preload issued
// MID-kernel (after staging regs die) so the epilogue has no L2-miss tail. ----
__global__ __launch_bounds__(256, 5) void k_edgemlp_mfma(
    const float* __restrict__ nf, const float* __restrict__ ef_in,
    const int* __restrict__ src, const int* __restrict__ dst,
    const u16* __restrict__ W1T, const float* __restrict__ b1,
    const float* __restrict__ lg, const float* __restrict__ lb,
    const u16* __restrict__ W2T, const float* __restrict__ b2,
    float* __restrict__ ef_out, int E) {
    __shared__ __align__(16) u16 A1[64 * 200];      // bf16 A tile (reused as A2), 25.6KB
    __shared__ float ps[4][64], pq[4][64];          // 2KB
    int tid = threadIdx.x;
    int w = tid >> 6, lane = tid & 63;
    int e0 = blockIdx.x * 64;
    int ebase = e0 + w * 16;                        // wave-local 16 edges
    int m16 = lane & 15, quad = lane >> 4, kq = quad * 8;
    int col2 = w * 16 + m16;

    // ---- wave-local index prefetch: lanes 0..15 src, 16..31 dst (one coalesced shot)
    int idxv = 0;
    if (lane < 16)      idxv = src[min(ebase + lane, E - 1)];
    else if (lane < 32) idxv = dst[min(ebase + lane - 16, E - 1)];

    // ---- stage 2 edges/iter: lane<32 -> edge 2*it, lane>=32 -> edge 2*it+1.
    {
        int half = lane >> 5;
        int c2 = (lane & 31) << 1;
        #pragma unroll
        for (int it = 0; it < 8; ++it) {
            int eloc = 2 * it + half;
            int ge = ebase + eloc;
            int sA = __shfl(idxv, eloc);
            int dA = __shfl(idxv, 16 + eloc);
            float2 za = make_float2(0.f, 0.f), zb = za, zf = za;
            if (ge < E) {
                za = *(const float2*)&nf[(size_t)sA * D + c2];
                zb = *(const float2*)&nf[(size_t)dA * D + c2];
                zf = *(const float2*)&ef_in[(size_t)ge * D + c2];
            }
            unsigned su = (unsigned)f2bf(za.x + zb.x) | ((unsigned)f2bf(za.y + zb.y) << 16);
            unsigned du = (unsigned)f2bf(fabsf(za.x - zb.x)) | ((unsigned)f2bf(fabsf(za.y - zb.y)) << 16);
            unsigned fu = (unsigned)f2bf(zf.x) | ((unsigned)f2bf(zf.y) << 16);
            int row = w * 16 + eloc;
            *(unsigned*)&A1[row * 200 + c2]       = su;
            *(unsigned*)&A1[row * 200 + 64 + c2]  = du;
            *(unsigned*)&A1[row * 200 + 128 + c2] = fu;
        }
    }
    __syncthreads();

    // ---- mid-kernel residual preload: staging regs dead now; these 16 loads
    // ride out GEMM1+LN+GEMM2 and land warm for the epilogue. ----
    float rf[4][4];
    #pragma unroll
    for (int mt = 0; mt < 4; ++mt)
        #pragma unroll
        for (int r = 0; r < 4; ++r) {
            int ge = e0 + mt * 16 + quad * 4 + r;
            rf[mt][r] = (ge < E) ? ef_in[(size_t)ge * D + col2] : 0.f;
        }

    // ---- GEMM1: wave w owns cols [w*48, w*48+48): 4 m-tiles x 3 n-tiles ----
    f32x4 acc[4][3];
    #pragma unroll
    for (int nt = 0; nt < 3; ++nt) {
        float bv = b1[w * 48 + nt * 16 + m16];
        #pragma unroll
        for (int mt = 0; mt < 4; ++mt) {
            acc[mt][nt][0] = bv; acc[mt][nt][1] = bv;
            acc[mt][nt][2] = bv; acc[mt][nt][3] = bv;
        }
    }
    #pragma unroll
    for (int ks = 0; ks < 6; ++ks) {
        int ko = ks * 32 + kq;
        bf16x8 af0 = *(const bf16x8*)&A1[(0  + m16) * 200 + ko];
        bf16x8 af1 = *(const bf16x8*)&A1[(16 + m16) * 200 + ko];
        bf16x8 af2 = *(const bf16x8*)&A1[(32 + m16) * 200 + ko];
        bf16x8 af3 = *(const bf16x8*)&A1[(48 + m16) * 200 + ko];
        #pragma unroll
        for (int nt = 0; nt < 3; ++nt) {
            bf16x8 bfr = *(const bf16x8*)&W1T[(w * 48 + nt * 16 + m16) * D3 + ko];
            acc[0][nt] = __builtin_amdgcn_mfma_f32_16x16x32_bf16(af0, bfr, acc[0][nt], 0, 0, 0);
            acc[1][nt] = __builtin_amdgcn_mfma_f32_16x16x32_bf16(af1, bfr, acc[1][nt], 0, 0, 0);
            acc[2][nt] = __builtin_amdgcn_mfma_f32_16x16x32_bf16(af2, bfr, acc[2][nt], 0, 0, 0);
            acc[3][nt] = __builtin_amdgcn_mfma_f32_16x16x32_bf16(af3, bfr, acc[3][nt], 0, 0, 0);
        }
    }

    // ---- LN partial stats per m-tile -> ps/pq ----
    #pragma unroll
    for (int mt = 0; mt < 4; ++mt) {
        float s8[4], q8[4];
        #pragma unroll
        for (int r = 0; r < 4; ++r) {
            float v0 = acc[mt][0][r], v1 = acc[mt][1][r], v2 = acc[mt][2][r];
            s8[r] = v0 + v1 + v2;
            q8[r] = v0 * v0 + v1 * v1 + v2 * v2;
        }
        #pragma unroll
        for (int off = 1; off < 16; off <<= 1) {
            #pragma unroll
            for (int r = 0; r < 4; ++r) {
                s8[r] += __shfl_xor(s8[r], off);
                q8[r] += __shfl_xor(q8[r], off);
            }
        }
        if (m16 == 0) {
            #pragma unroll
            for (int r = 0; r < 4; ++r) {
                int row = mt * 16 + quad * 4 + r;
                ps[w][row] = s8[r];
                pq[w][row] = q8[r];
            }
        }
    }
    __syncthreads();

    // ---- every wave computes all 64 rows' mu/rstd redundantly (registers) ----
    float mu_l, rs_l;
    {
        float s = ps[0][lane] + ps[1][lane] + ps[2][lane] + ps[3][lane];
        float q = pq[0][lane] + pq[1][lane] + pq[2][lane] + pq[3][lane];
        mu_l = s * (1.f / 192.f);
        rs_l = rsqrtf(q * (1.f / 192.f) - mu_l * mu_l + 1e-5f);
    }

    // ---- LN + relu in registers, write bf16 A2 tile (overwrites A1) ----
    {
        float gg0 = lg[w * 48 + 0 * 16 + m16], bb0 = lb[w * 48 + 0 * 16 + m16];
        float gg1 = lg[w * 48 + 1 * 16 + m16], bb1 = lb[w * 48 + 1 * 16 + m16];
        float gg2 = lg[w * 48 + 2 * 16 + m16], bb2 = lb[w * 48 + 2 * 16 + m16];
        #pragma unroll
        for (int mt = 0; mt < 4; ++mt) {
            #pragma unroll
            for (int r = 0; r < 4; ++r) {
                int row = mt * 16 + quad * 4 + r;
                float mu = __shfl(mu_l, row);
                float rstd = __shfl(rs_l, row);
                float v0 = (acc[mt][0][r] - mu) * rstd * gg0 + bb0;
                float v1 = (acc[mt][1][r] - mu) * rstd * gg1 + bb1;
                float v2 = (acc[mt][2][r] - mu) * rstd * gg2 + bb2;
                A1[row * 200 + w * 48 + 0 * 16 + m16] = f2bf(fmaxf(v0, 0.f));
                A1[row * 200 + w * 48 + 1 * 16 + m16] = f2bf(fmaxf(v1, 0.f));
                A1[row * 200 + w * 48 + 2 * 16 + m16] = f2bf(fmaxf(v2, 0.f));
            }
        }
    }
    __syncthreads();

    // ---- GEMM2: wave w owns cols w*16..w*16+15, 4 m-tiles ----
    f32x4 acc2[4];
    {
        float bv = b2[col2];
        #pragma unroll
        for (int mt = 0; mt < 4; ++mt) {
            acc2[mt][0] = bv; acc2[mt][1] = bv; acc2[mt][2] = bv; acc2[mt][3] = bv;
        }
    }
    #pragma unroll
    for (int ks = 0; ks < 6; ++ks) {
        int ko = ks * 32 + kq;
        bf16x8 b2f = *(const bf16x8*)&W2T[col2 * D3 + ko];
        bf16x8 a2f0 = *(const bf16x8*)&A1[(0  + m16) * 200 + ko];
        bf16x8 a2f1 = *(const bf16x8*)&A1[(16 + m16) * 200 + ko];
        bf16x8 a2f2 = *(const bf16x8*)&A1[(32 + m16) * 200 + ko];
        bf16x8 a2f3 = *(const bf16x8*)&A1[(48 + m16) * 200 + ko];
        acc2[0] = __builtin_amdgcn_mfma_f32_16x16x32_bf16(a2f0, b2f, acc2[0], 0, 0, 0);
        acc2[1] = __builtin_amdgcn_mfma_f32_16x16x32_bf16(a2f1, b2f, acc2[1], 0, 0, 0);
        acc2[2] = __builtin_amdgcn_mfma_f32_16x16x32_bf16(a2f2, b2f, acc2[2], 0, 0, 0);
        acc2[3] = __builtin_amdgcn_mfma_f32_16x16x32_bf16(a2f3, b2f, acc2[3], 0, 0, 0);
    }
    // ---- store + residual (preloaded mid-kernel) ----
    #pragma unroll
    for (int mt = 0; mt < 4; ++mt) {
        int row0 = mt * 16 + quad * 4;
        #pragma unroll
        for (int r = 0; r < 4; ++r) {
            int ge = e0 + row0 + r;
            if (ge < E) {
                size_t o = (size_t)ge * D + col2;
                ef_out[o] = acc2[mt][r] + rf[mt][r];
            }
        }
    }
}

extern "C" void kernel_launch(void* const* d_in, const int* in_sizes, int n_in,
                              void* d_out, int out_size, void* d_ws, size_t ws_size,
                              hipStream_t stream) {
    const float* nf_in0   = (const float*)d_in[0];
    const float* ef_in0   = (const float*)d_in[1];
    const int*   eidx     = (const int*)d_in[2];
    const float* W_lin    = (const float*)d_in[3];
    const float* W_edge   = (const float*)d_in[4];
    const float* att_src  = (const float*)d_in[5];
    const float* att_dst  = (const float*)d_in[6];
    const float* att_edge = (const float*)d_in[7];
    const float* biasc    = (const float*)d_in[8];
    const float* ln_g     = (const float*)d_in[9];
    const float* ln_b     = (const float*)d_in[10];
    const float* eW1      = (const float*)d_in[11];
    const float* eb1      = (const float*)d_in[12];
    const float* eln_g    = (const float*)d_in[13];
    const float* eln_b    = (const float*)d_in[14];
    const float* eW2      = (const float*)d_in[15];
    const float* eb2      = (const float*)d_in[16];

    int N = in_sizes[0] / D;
    int E = in_sizes[1] / D;
    const int* srcp = eidx;
    const int* dstp = eidx + E;

    float* ws        = (float*)d_ws;
    float* x         = ws;                               // N*256
    float* alpha_csr = x + (size_t)N * HC;               // E*4 (16B aligned)
    float* a_src     = alpha_csr + (size_t)E * H;        // N*4
    float* a_dst     = a_src + (size_t)N * H;            // N*4
    float* nf_ln     = a_dst + (size_t)N * H;            // N*64
    float* weff      = nf_ln + (size_t)N * D;            // L*256
    float* w_asd     = weff + NLAYERS * HC;              // L*512
    u16*   W1T       = (u16*)(w_asd + NLAYERS * 512);    // L*192*192 bf16
    u16*   W2T       = W1T + (size_t)NLAYERS * D3 * D3;  // L*64*192 bf16
    u16*   WLh       = W2T + (size_t)NLAYERS * D3 * D;   // L*256*64 bf16 (W_lin^T hi)
    u16*   WLl       = WLh + (size_t)NLAYERS * HC * D;   // L*256*64 bf16 (W_lin^T lo)
    int*   rowptr    = (int*)(WLl + (size_t)NLAYERS * HC * D); // N+1
    int*   head      = rowptr + (N + 1);                 // N
    int*   csrpos    = head + N;                         // E
    int*   perm_src  = csrpos + (size_t)E;               // E

    float* out_nf = (float*)d_out;
    float* out_ef = out_nf + (size_t)N * D;

    // ---- once per launch: weights + CSR ----
    {
        int total = NLAYERS * D3 * D3 + NLAYERS * D3 * D;
        k_cvtw<<<(total + 255) / 256, 256, 0, stream>>>(eW1, eW2, W1T, W2T);
        k_cvtwl<<<(NLAYERS * HC * D + 255) / 256, 256, 0, stream>>>(W_lin, WLh, WLl);
        k_weffs<<<NLAYERS, 256, 0, stream>>>(W_edge, att_edge, W_lin, att_src, att_dst,
                                             weff, w_asd);
        hipMemsetAsync(head, 0, (size_t)N * sizeof(int), stream);  // head used as deg first
        k_hist<<<(E + 255) / 256, 256, 0, stream>>>(dstp, head, E);
        k_scan<<<1, 1024, 0, stream>>>(head, rowptr, head, N, E);  // deg in, head out
        k_scatter<<<(E + 255) / 256, 256, 0, stream>>>(srcp, dstp, head, csrpos, perm_src, E);
    }

    for (int l = 0; l < NLAYERS; ++l) {
        const float* nf_cur = (l == 0) ? nf_in0 : nf_ln;
        const float* ef_cur = (l == 0) ? ef_in0 : out_ef;
        int relu_in = (l > 0) ? 1 : 0;

        k_nodeproj_mfma<<<(N + 31) / 32, 256, 0, stream>>>(
            nf_cur, WLh + (size_t)l * HC * D, WLl + (size_t)l * HC * D,
            w_asd + (size_t)l * 512, x, a_src, a_dst, N, relu_in);
        k_alpha<<<(E + 15) / 16, 256, 0, stream>>>(ef_cur, weff + (size_t)l * HC, srcp, dstp,
                                                   a_src, a_dst, csrpos, alpha_csr, E);
        k_gat<<<(N + 3) / 4, 256, 0, stream>>>(x, alpha_csr, rowptr, perm_src,
                                               biasc + l * D, ln_g + l * D, ln_b + l * D,
                                               nf_ln, (l == NLAYERS - 1) ? out_nf : nullptr, N);
        k_edgemlp_mfma<<<(E + 63) / 64, 256, 0, stream>>>(nf_ln, ef_cur, srcp, dstp,
                                                          W1T + (size_t)l * D3 * D3, eb1 + l * D3,
                                                          eln_g + l * D3, eln_b + l * D3,
                                                          W2T + (size_t)l * D3 * D, eb2 + l * D,
                                                          out_ef, E);
    }
}

// Round 8
// 1007.286 us; speedup vs baseline: 1.3742x; 1.3742x over previous
//
#include <hip/hip_runtime.h>
#include <math.h>

#define NLAYERS 4
#define H 4
#define C 64
#define D 64
#define HC 256     // H*C
#define D3 192     // 3*D
#define NEG 0.2f

typedef float f32x4 __attribute__((ext_vector_type(4)));
typedef short bf16x8 __attribute__((ext_vector_type(8)));
typedef unsigned short u16;

// fp32 -> bf16 round-to-nearest-even
__device__ __forceinline__ u16 f2bf(float f) {
    unsigned u = __float_as_uint(f);
    u += 0x7FFFu + ((u >> 16) & 1u);
    return (u16)(u >> 16);
}
__device__ __forceinline__ float bf2f(u16 h) {
    return __uint_as_float((unsigned)h << 16);
}

// ---- K0: per-layer small weight folds. One block PER LAYER (4 blocks, one launch). ----
__global__ void k_weffs(const float* __restrict__ W_edge, const float* __restrict__ att_edge,
                        const float* __restrict__ W_lin, const float* __restrict__ att_s,
                        const float* __restrict__ att_d,
                        float* __restrict__ weff, float* __restrict__ w_asd) {
    int l = blockIdx.x;
    const float* We = W_edge + (size_t)l * D * HC;
    const float* Wl = W_lin + (size_t)l * D * HC;
    const float* ae = att_edge + l * H * C;
    const float* as_ = att_s + l * H * C;
    const float* ad = att_d + l * H * C;
    int t = threadIdx.x;
    int d = t >> 2, h = t & 3;
    float se = 0.f, ss = 0.f, sd = 0.f;
    #pragma unroll
    for (int c = 0; c < C; ++c) {
        float we = We[d * HC + h * C + c];
        float wl = Wl[d * HC + h * C + c];
        se = fmaf(we, ae[h * C + c], se);
        ss = fmaf(wl, as_[h * C + c], ss);
        sd = fmaf(wl, ad[h * C + c], sd);
    }
    weff[l * HC + d * 4 + h] = se;
    w_asd[l * 512 + d * 8 + h] = ss;
    w_asd[l * 512 + d * 8 + 4 + h] = sd;
}

// ---- K0b: convert W1 -> W1^T bf16, W2 -> W2^T bf16 ----
__global__ void k_cvtw(const float* __restrict__ W1, const float* __restrict__ W2,
                       u16* __restrict__ W1T, u16* __restrict__ W2T) {
    int i = blockIdx.x * 256 + threadIdx.x;
    if (i < NLAYERS * D3 * D3) {
        int l = i / (D3 * D3), r = i % (D3 * D3);
        int n = r / D3, k = r % D3;
        W1T[i] = f2bf(W1[l * D3 * D3 + k * D3 + n]);
    } else {
        int j = i - NLAYERS * D3 * D3;
        if (j < NLAYERS * D3 * D) {
            int l = j / (D3 * D), r = j % (D3 * D);
            int n = r / D3, k = r % D3;
            W2T[j] = f2bf(W2[l * D3 * D + k * D + n]);
        }
    }
}

// ---- K0c: W_lin -> transposed split-bf16 (hi + residual-lo). WLT[l][o][d]. ----
__global__ void k_cvtwl(const float* __restrict__ W_lin,
                        u16* __restrict__ WTh, u16* __restrict__ WTl) {
    int i = blockIdx.x * 256 + threadIdx.x;
    if (i >= NLAYERS * HC * D) return;
    int l = i / (HC * D), r = i % (HC * D);
    int o = r / D, d = r % D;
    float v = W_lin[(size_t)l * D * HC + d * HC + o];
    u16 h = f2bf(v);
    WTh[i] = h;
    WTl[i] = f2bf(v - bf2f(h));
}

// ---- CSR build (once per launch) ----
__global__ void k_hist(const int* __restrict__ dst, int* __restrict__ deg, int E) {
    int i = blockIdx.x * blockDim.x + threadIdx.x;
    if (i < E) atomicAdd(&deg[dst[i]], 1);
}

__global__ void k_scan(const int* __restrict__ deg, int* __restrict__ rowptr,
                       int* __restrict__ head, int N, int E) {
    __shared__ int lds[1024];
    int t = threadIdx.x;
    int chunk = (N + 1023) / 1024;
    int begin = t * chunk, end = min(begin + chunk, N);
    int sum = 0;
    for (int i = begin; i < end; ++i) sum += deg[i];
    lds[t] = sum;
    __syncthreads();
    for (int off = 1; off < 1024; off <<= 1) {
        int v = (t >= off) ? lds[t - off] : 0;
        __syncthreads();
        lds[t] += v;
        __syncthreads();
    }
    int running = (t == 0) ? 0 : lds[t - 1];
    for (int i = begin; i < end; ++i) {
        int dg = deg[i];          // read BEFORE head[i] overwrite (deg aliases head)
        rowptr[i] = running;
        head[i] = running;
        running += dg;
    }
    if (t == 0) rowptr[N] = E;
}

__global__ void k_scatter(const int* __restrict__ src, const int* __restrict__ dst,
                          int* __restrict__ head, int* __restrict__ csrpos,
                          int* __restrict__ perm_src, int E) {
    int i = blockIdx.x * blockDim.x + threadIdx.x;
    if (i < E) {
        int d = dst[i];
        int pos = atomicAdd(&head[d], 1);
        csrpos[i] = pos;
        perm_src[pos] = src[i];
    }
}

// ---- K1 (MFMA): x = nf @ W_lin via split-bf16 (fp32-equivalent accuracy). ----
__global__ __launch_bounds__(256, 4) void k_nodeproj_mfma(
    const float* __restrict__ nf, const u16* __restrict__ WTh, const u16* __restrict__ WTl,
    const float* __restrict__ w_asd, float* __restrict__ x,
    float* __restrict__ a_src, float* __restrict__ a_dst, int N, int relu_in) {
    __shared__ __align__(16) u16 s_ah[32 * 72];    // bf16 hi tile, pad 72 (2-way bank max)
    __shared__ __align__(16) u16 s_al[32 * 72];    // bf16 residual tile
    __shared__ __align__(16) float s_nf[32][68];   // fp32 tile for attention dots
    __shared__ __align__(16) float s_wasd[512];
    int tid = threadIdx.x;
    int w = tid >> 6, lane = tid & 63;
    int n0 = blockIdx.x << 5;

    if (tid < 128) *(float4*)&s_wasd[tid * 4] = *(const float4*)&w_asd[tid * 4];

    // stage: thread -> (row = tid>>3, 8 cols at (tid&7)*8). Coalesced 256B per row.
    {
        int r = tid >> 3, c0 = (tid & 7) << 3;
        int n = n0 + r;
        float4 v0 = make_float4(0.f, 0.f, 0.f, 0.f), v1 = v0;
        if (n < N) {
            v0 = *(const float4*)&nf[(size_t)n * D + c0];
            v1 = *(const float4*)&nf[(size_t)n * D + c0 + 4];
        }
        if (relu_in) {
            v0.x = fmaxf(v0.x, 0.f); v0.y = fmaxf(v0.y, 0.f);
            v0.z = fmaxf(v0.z, 0.f); v0.w = fmaxf(v0.w, 0.f);
            v1.x = fmaxf(v1.x, 0.f); v1.y = fmaxf(v1.y, 0.f);
            v1.z = fmaxf(v1.z, 0.f); v1.w = fmaxf(v1.w, 0.f);
        }
        *(float4*)&s_nf[r][c0] = v0;
        *(float4*)&s_nf[r][c0 + 4] = v1;
        float vv[8] = {v0.x, v0.y, v0.z, v0.w, v1.x, v1.y, v1.z, v1.w};
        bf16x8 hv, lv;
        #pragma unroll
        for (int j = 0; j < 8; ++j) {
            u16 h = f2bf(vv[j]);
            hv[j] = (short)h;
            lv[j] = (short)f2bf(vv[j] - bf2f(h));
        }
        *(bf16x8*)&s_ah[r * 72 + c0] = hv;
        *(bf16x8*)&s_al[r * 72 + c0] = lv;
    }
    __syncthreads();

    int m16 = lane & 15, quad = lane >> 4, kq = quad * 8;
    f32x4 acc[2][4];
    #pragma unroll
    for (int mt = 0; mt < 2; ++mt)
        #pragma unroll
        for (int nt = 0; nt < 4; ++nt) {
            acc[mt][nt][0] = 0.f; acc[mt][nt][1] = 0.f;
            acc[mt][nt][2] = 0.f; acc[mt][nt][3] = 0.f;
        }
    #pragma unroll
    for (int ks = 0; ks < 2; ++ks) {
        int ko = ks * 32 + kq;
        bf16x8 ah0 = *(const bf16x8*)&s_ah[m16 * 72 + ko];
        bf16x8 ah1 = *(const bf16x8*)&s_ah[(16 + m16) * 72 + ko];
        bf16x8 al0 = *(const bf16x8*)&s_al[m16 * 72 + ko];
        bf16x8 al1 = *(const bf16x8*)&s_al[(16 + m16) * 72 + ko];
        #pragma unroll
        for (int nt = 0; nt < 4; ++nt) {
            int col = w * 64 + nt * 16 + m16;
            bf16x8 bh = *(const bf16x8*)&WTh[col * D + ko];
            bf16x8 bl = *(const bf16x8*)&WTl[col * D + ko];
            acc[0][nt] = __builtin_amdgcn_mfma_f32_16x16x32_bf16(ah0, bh, acc[0][nt], 0, 0, 0);
            acc[0][nt] = __builtin_amdgcn_mfma_f32_16x16x32_bf16(al0, bh, acc[0][nt], 0, 0, 0);
            acc[0][nt] = __builtin_amdgcn_mfma_f32_16x16x32_bf16(ah0, bl, acc[0][nt], 0, 0, 0);
            acc[1][nt] = __builtin_amdgcn_mfma_f32_16x16x32_bf16(ah1, bh, acc[1][nt], 0, 0, 0);
            acc[1][nt] = __builtin_amdgcn_mfma_f32_16x16x32_bf16(al1, bh, acc[1][nt], 0, 0, 0);
            acc[1][nt] = __builtin_amdgcn_mfma_f32_16x16x32_bf16(ah1, bl, acc[1][nt], 0, 0, 0);
        }
    }
    #pragma unroll
    for (int mt = 0; mt < 2; ++mt) {
        #pragma unroll
        for (int nt = 0; nt < 4; ++nt) {
            int col = w * 64 + nt * 16 + m16;
            #pragma unroll
            for (int r = 0; r < 4; ++r) {
                int n = n0 + mt * 16 + quad * 4 + r;
                if (n < N) x[(size_t)n * HC + col] = acc[mt][nt][r];
            }
        }
    }

    // attention scalars: one (node, o) dot per thread, all 256 active (fp32).
    {
        int nloc = tid >> 3, o = tid & 7;
        float s = 0.f;
        #pragma unroll
        for (int d = 0; d < 64; ++d)
            s = fmaf(s_nf[nloc][d], s_wasd[d * 8 + o], s);
        int n = n0 + nloc;
        if (n < N) {
            if (o < 4) a_src[n * 4 + o] = s;
            else       a_dst[n * 4 + (o - 4)] = s;
        }
    }
}

// ---- K2: per-edge alpha (layer 0 only), 16 lanes per edge, float4 loads. ----
__global__ void k_alpha(const float* __restrict__ ef, const float* __restrict__ weff,
                        const int* __restrict__ src, const int* __restrict__ dst,
                        const float* __restrict__ a_src, const float* __restrict__ a_dst,
                        const int* __restrict__ csrpos, float* __restrict__ alpha_csr, int E) {
    int wave = (int)((blockIdx.x * blockDim.x + threadIdx.x) >> 6);
    int lane = threadIdx.x & 63;
    int sub = lane >> 4, li = lane & 15;
    int e = wave * 4 + sub;
    if (e >= E) return;
    float4 efv = *(const float4*)&ef[(size_t)e * D + li * 4];
    float4 w0 = *(const float4*)&weff[(li * 4 + 0) * 4];
    float4 w1 = *(const float4*)&weff[(li * 4 + 1) * 4];
    float4 w2 = *(const float4*)&weff[(li * 4 + 2) * 4];
    float4 w3 = *(const float4*)&weff[(li * 4 + 3) * 4];
    float p0 = efv.x * w0.x + efv.y * w1.x + efv.z * w2.x + efv.w * w3.x;
    float p1 = efv.x * w0.y + efv.y * w1.y + efv.z * w2.y + efv.w * w3.y;
    float p2 = efv.x * w0.z + efv.y * w1.z + efv.z * w2.z + efv.w * w3.z;
    float p3 = efv.x * w0.w + efv.y * w1.w + efv.z * w2.w + efv.w * w3.w;
    #pragma unroll
    for (int off = 1; off < 16; off <<= 1) {
        p0 += __shfl_xor(p0, off);
        p1 += __shfl_xor(p1, off);
        p2 += __shfl_xor(p2, off);
        p3 += __shfl_xor(p3, off);
    }
    if (li < 4) {
        float p = (li == 0) ? p0 : (li == 1) ? p1 : (li == 2) ? p2 : p3;
        int s = src[e], dd = dst[e];
        float a = p + a_src[s * 4 + li] + a_dst[dd * 4 + li];
        a = (a > 0.f) ? a : NEG * a;
        alpha_csr[(size_t)csrpos[e] * 4 + li] = a;
    }
}

// ---- K2b: alpha from precomputed p (layers 1..3). One thread per (edge, head). ----
__global__ void k_alpha_lite(const float* __restrict__ palpha,
                             const int* __restrict__ src, const int* __restrict__ dst,
                             const float* __restrict__ a_src, const float* __restrict__ a_dst,
                             const int* __restrict__ csrpos, float* __restrict__ alpha_csr, int E) {
    int i = blockIdx.x * 256 + threadIdx.x;
    if (i >= E * 4) return;
    int e = i >> 2, h = i & 3;
    float a = palpha[i] + a_src[src[e] * 4 + h] + a_dst[dst[e] * 4 + h];
    a = (a > 0.f) ? a : NEG * a;
    alpha_csr[(size_t)csrpos[e] * 4 + h] = a;
}

// ---- K3: fused per-dst GAT (R6 version: exp stored back, 4-deep pass C). ----
__global__ void k_gat(const float* __restrict__ x, float* __restrict__ alpha_csr,
                      const int* __restrict__ rowptr, const int* __restrict__ perm_src,
                      const float* __restrict__ bias, const float* __restrict__ g,
                      const float* __restrict__ b, float* __restrict__ nf_ln,
                      float* __restrict__ out2, int N) {
    int n = (int)((blockIdx.x * blockDim.x + threadIdx.x) >> 6);
    int lane = threadIdx.x & 63;
    if (n >= N) return;
    int s = rowptr[n], e = rowptr[n + 1];
    int deg = e - s;
    // pass A: per-head max
    float m0 = -1e30f, m1 = -1e30f, m2 = -1e30f, m3 = -1e30f;
    for (int i = lane; i < deg; i += 64) {
        const float4 a = *(const float4*)&alpha_csr[(size_t)(s + i) * 4];
        m0 = fmaxf(m0, a.x); m1 = fmaxf(m1, a.y);
        m2 = fmaxf(m2, a.z); m3 = fmaxf(m3, a.w);
    }
    #pragma unroll
    for (int off = 32; off; off >>= 1) {
        m0 = fmaxf(m0, __shfl_xor(m0, off)); m1 = fmaxf(m1, __shfl_xor(m1, off));
        m2 = fmaxf(m2, __shfl_xor(m2, off)); m3 = fmaxf(m3, __shfl_xor(m3, off));
    }
    // pass B: exp + sum; store exp back (segment exclusive to this wave)
    float d0 = 0.f, d1 = 0.f, d2 = 0.f, d3 = 0.f;
    for (int i = lane; i < deg; i += 64) {
        float4 a = *(const float4*)&alpha_csr[(size_t)(s + i) * 4];
        a.x = expf(a.x - m0); a.y = expf(a.y - m1);
        a.z = expf(a.z - m2); a.w = expf(a.w - m3);
        *(float4*)&alpha_csr[(size_t)(s + i) * 4] = a;
        d0 += a.x; d1 += a.y; d2 += a.z; d3 += a.w;
    }
    #pragma unroll
    for (int off = 32; off; off >>= 1) {
        d0 += __shfl_xor(d0, off); d1 += __shfl_xor(d1, off);
        d2 += __shfl_xor(d2, off); d3 += __shfl_xor(d3, off);
    }
    float i0 = 0.25f / (d0 + 1e-16f), i1 = 0.25f / (d1 + 1e-16f);
    float i2 = 0.25f / (d2 + 1e-16f), i3 = 0.25f / (d3 + 1e-16f);
    // pass C: aggregate, 4 edges in flight; weights are pure mul now
    float ac0 = 0.f, ac1 = 0.f, ac2 = 0.f, ac3 = 0.f;
    int j = 0;
    for (; j + 3 < deg; j += 4) {
        const float4 a0 = *(const float4*)&alpha_csr[(size_t)(s + j + 0) * 4];
        const float4 a1 = *(const float4*)&alpha_csr[(size_t)(s + j + 1) * 4];
        const float4 a2 = *(const float4*)&alpha_csr[(size_t)(s + j + 2) * 4];
        const float4 a3 = *(const float4*)&alpha_csr[(size_t)(s + j + 3) * 4];
        int s0 = perm_src[s + j + 0], s1 = perm_src[s + j + 1];
        int s2 = perm_src[s + j + 2], s3 = perm_src[s + j + 3];
        const float* x0 = x + (size_t)s0 * HC;
        const float* x1 = x + (size_t)s1 * HC;
        const float* x2 = x + (size_t)s2 * HC;
        const float* x3 = x + (size_t)s3 * HC;
        ac0 += a0.x * i0 * x0[lane] + a0.y * i1 * x0[64 + lane]
             + a0.z * i2 * x0[128 + lane] + a0.w * i3 * x0[192 + lane];
        ac1 += a1.x * i0 * x1[lane] + a1.y * i1 * x1[64 + lane]
             + a1.z * i2 * x1[128 + lane] + a1.w * i3 * x1[192 + lane];
        ac2 += a2.x * i0 * x2[lane] + a2.y * i1 * x2[64 + lane]
             + a2.z * i2 * x2[128 + lane] + a2.w * i3 * x2[192 + lane];
        ac3 += a3.x * i0 * x3[lane] + a3.y * i1 * x3[64 + lane]
             + a3.z * i2 * x3[128 + lane] + a3.w * i3 * x3[192 + lane];
    }
    for (; j < deg; ++j) {
        const float4 a = *(const float4*)&alpha_csr[(size_t)(s + j) * 4];
        int sidx = perm_src[s + j];
        const float* xr = x + (size_t)sidx * HC;
        ac0 += a.x * i0 * xr[lane] + a.y * i1 * xr[64 + lane]
             + a.z * i2 * xr[128 + lane] + a.w * i3 * xr[192 + lane];
    }
    float acc = (ac0 + ac1) + (ac2 + ac3);
    // bias + LN
    float v = acc + bias[lane];
    float sm = v;
    #pragma unroll
    for (int off = 32; off; off >>= 1) sm += __shfl_xor(sm, off);
    float mu = sm * (1.f / 64.f);
    float dv = v - mu;
    float q = dv * dv;
    #pragma unroll
    for (int off = 32; off; off >>= 1) q += __shfl_xor(q, off);
    float rstd = rsqrtf(q * (1.f / 64.f) + 1e-5f);
    float r = dv * rstd * g[lane] + b[lane];
    nf_ln[(size_t)n * D + lane] = r;
    if (out2) out2[(size_t)n * D + lane] = r;
}

// ---- K6: fused edge MLP (R6 body). New: optional fused next-layer alpha-dot —
// ef_out tile is dumped to LDS (A1 reused as fp32) and p[e][h] = ef_out·weffN
// is computed from LDS, killing the 82MB ef re-read in the next k_alpha. ----
__global__ __launch_bounds__(256, 5) void k_edgemlp_mfma(
    const float* __restrict__ nf, const float* __restrict__ ef_in,
    const int* __restrict__ src, const int* __restrict__ dst,
    const u16* __restrict__ W1T, const float* __restrict__ b1,
    const float* __restrict__ lg, const float* __restrict__ lb,
    const u16* __restrict__ W2T, const float* __restrict__ b2,
    float* __restrict__ ef_out, const float* __restrict__ weffN,
    float* __restrict__ palpha, int E) {
    __shared__ __align__(16) u16 A1[64 * 200];      // bf16 A tile (reused as A2, then fp32 ef tile)
    __shared__ float ps[4][64], pq[4][64];          // 2KB (reused as weffN stage)
    int tid = threadIdx.x;
    int w = tid >> 6, lane = tid & 63;
    int e0 = blockIdx.x * 64;
    int ebase = e0 + w * 16;                        // wave-local 16 edges

    // ---- wave-local index prefetch: lanes 0..15 src, 16..31 dst (one coalesced shot)
    int idxv = 0;
    if (lane < 16)      idxv = src[min(ebase + lane, E - 1)];
    else if (lane < 32) idxv = dst[min(ebase + lane - 16, E - 1)];

    // ---- stage 2 edges/iter: lane<32 -> edge 2*it, lane>=32 -> edge 2*it+1.
    {
        int half = lane >> 5;
        int c2 = (lane & 31) << 1;
        #pragma unroll
        for (int it = 0; it < 8; ++it) {
            int eloc = 2 * it + half;
            int ge = ebase + eloc;
            int sA = __shfl(idxv, eloc);
            int dA = __shfl(idxv, 16 + eloc);
            float2 za = make_float2(0.f, 0.f), zb = za, zf = za;
            if (ge < E) {
                za = *(const float2*)&nf[(size_t)sA * D + c2];
                zb = *(const float2*)&nf[(size_t)dA * D + c2];
                zf = *(const float2*)&ef_in[(size_t)ge * D + c2];
            }
            unsigned su = (unsigned)f2bf(za.x + zb.x) | ((unsigned)f2bf(za.y + zb.y) << 16);
            unsigned du = (unsigned)f2bf(fabsf(za.x - zb.x)) | ((unsigned)f2bf(fabsf(za.y - zb.y)) << 16);
            unsigned fu = (unsigned)f2bf(zf.x) | ((unsigned)f2bf(zf.y) << 16);
            int row = w * 16 + eloc;
            *(unsigned*)&A1[row * 200 + c2]       = su;
            *(unsigned*)&A1[row * 200 + 64 + c2]  = du;
            *(unsigned*)&A1[row * 200 + 128 + c2] = fu;
        }
    }
    __syncthreads();

    // ---- GEMM1: wave w owns cols [w*48, w*48+48): 4 m-tiles x 3 n-tiles ----
    int m16 = lane & 15, quad = lane >> 4, kq = quad * 8;
    f32x4 acc[4][3];
    #pragma unroll
    for (int nt = 0; nt < 3; ++nt) {
        float bv = b1[w * 48 + nt * 16 + m16];
        #pragma unroll
        for (int mt = 0; mt < 4; ++mt) {
            acc[mt][nt][0] = bv; acc[mt][nt][1] = bv;
            acc[mt][nt][2] = bv; acc[mt][nt][3] = bv;
        }
    }
    #pragma unroll
    for (int ks = 0; ks < 6; ++ks) {
        int ko = ks * 32 + kq;
        bf16x8 af0 = *(const bf16x8*)&A1[(0  + m16) * 200 + ko];
        bf16x8 af1 = *(const bf16x8*)&A1[(16 + m16) * 200 + ko];
        bf16x8 af2 = *(const bf16x8*)&A1[(32 + m16) * 200 + ko];
        bf16x8 af3 = *(const bf16x8*)&A1[(48 + m16) * 200 + ko];
        #pragma unroll
        for (int nt = 0; nt < 3; ++nt) {
            bf16x8 bfr = *(const bf16x8*)&W1T[(w * 48 + nt * 16 + m16) * D3 + ko];
            acc[0][nt] = __builtin_amdgcn_mfma_f32_16x16x32_bf16(af0, bfr, acc[0][nt], 0, 0, 0);
            acc[1][nt] = __builtin_amdgcn_mfma_f32_16x16x32_bf16(af1, bfr, acc[1][nt], 0, 0, 0);
            acc[2][nt] = __builtin_amdgcn_mfma_f32_16x16x32_bf16(af2, bfr, acc[2][nt], 0, 0, 0);
            acc[3][nt] = __builtin_amdgcn_mfma_f32_16x16x32_bf16(af3, bfr, acc[3][nt], 0, 0, 0);
        }
    }

    // ---- LN partial stats per m-tile -> ps/pq ----
    #pragma unroll
    for (int mt = 0; mt < 4; ++mt) {
        float s8[4], q8[4];
        #pragma unroll
        for (int r = 0; r < 4; ++r) {
            float v0 = acc[mt][0][r], v1 = acc[mt][1][r], v2 = acc[mt][2][r];
            s8[r] = v0 + v1 + v2;
            q8[r] = v0 * v0 + v1 * v1 + v2 * v2;
        }
        #pragma unroll
        for (int off = 1; off < 16; off <<= 1) {
            #pragma unroll
            for (int r = 0; r < 4; ++r) {
                s8[r] += __shfl_xor(s8[r], off);
                q8[r] += __shfl_xor(q8[r], off);
            }
        }
        if (m16 == 0) {
            #pragma unroll
            for (int r = 0; r < 4; ++r) {
                int row = mt * 16 + quad * 4 + r;
                ps[w][row] = s8[r];
                pq[w][row] = q8[r];
            }
        }
    }
    __syncthreads();

    // ---- every wave computes all 64 rows' mu/rstd redundantly (registers) ----
    float mu_l, rs_l;
    {
        float s = ps[0][lane] + ps[1][lane] + ps[2][lane] + ps[3][lane];
        float q = pq[0][lane] + pq[1][lane] + pq[2][lane] + pq[3][lane];
        mu_l = s * (1.f / 192.f);
        rs_l = rsqrtf(q * (1.f / 192.f) - mu_l * mu_l + 1e-5f);
    }

    // ---- LN + relu in registers, write bf16 A2 tile (overwrites A1) ----
    {
        float gg0 = lg[w * 48 + 0 * 16 + m16], bb0 = lb[w * 48 + 0 * 16 + m16];
        float gg1 = lg[w * 48 + 1 * 16 + m16], bb1 = lb[w * 48 + 1 * 16 + m16];
        float gg2 = lg[w * 48 + 2 * 16 + m16], bb2 = lb[w * 48 + 2 * 16 + m16];
        #pragma unroll
        for (int mt = 0; mt < 4; ++mt) {
            #pragma unroll
            for (int r = 0; r < 4; ++r) {
                int row = mt * 16 + quad * 4 + r;
                float mu = __shfl(mu_l, row);
                float rstd = __shfl(rs_l, row);
                float v0 = (acc[mt][0][r] - mu) * rstd * gg0 + bb0;
                float v1 = (acc[mt][1][r] - mu) * rstd * gg1 + bb1;
                float v2 = (acc[mt][2][r] - mu) * rstd * gg2 + bb2;
                A1[row * 200 + w * 48 + 0 * 16 + m16] = f2bf(fmaxf(v0, 0.f));
                A1[row * 200 + w * 48 + 1 * 16 + m16] = f2bf(fmaxf(v1, 0.f));
                A1[row * 200 + w * 48 + 2 * 16 + m16] = f2bf(fmaxf(v2, 0.f));
            }
        }
    }
    __syncthreads();

    // ---- GEMM2: wave w owns cols w*16..w*16+15, 4 m-tiles ----
    int col2 = w * 16 + m16;
    f32x4 acc2[4];
    {
        float bv = b2[col2];
        #pragma unroll
        for (int mt = 0; mt < 4; ++mt) {
            acc2[mt][0] = bv; acc2[mt][1] = bv; acc2[mt][2] = bv; acc2[mt][3] = bv;
        }
    }
    #pragma unroll
    for (int ks = 0; ks < 6; ++ks) {
        int ko = ks * 32 + kq;
        bf16x8 b2f = *(const bf16x8*)&W2T[col2 * D3 + ko];
        bf16x8 a2f0 = *(const bf16x8*)&A1[(0  + m16) * 200 + ko];
        bf16x8 a2f1 = *(const bf16x8*)&A1[(16 + m16) * 200 + ko];
        bf16x8 a2f2 = *(const bf16x8*)&A1[(32 + m16) * 200 + ko];
        bf16x8 a2f3 = *(const bf16x8*)&A1[(48 + m16) * 200 + ko];
        acc2[0] = __builtin_amdgcn_mfma_f32_16x16x32_bf16(a2f0, b2f, acc2[0], 0, 0, 0);
        acc2[1] = __builtin_amdgcn_mfma_f32_16x16x32_bf16(a2f1, b2f, acc2[1], 0, 0, 0);
        acc2[2] = __builtin_amdgcn_mfma_f32_16x16x32_bf16(a2f2, b2f, acc2[2], 0, 0, 0);
        acc2[3] = __builtin_amdgcn_mfma_f32_16x16x32_bf16(a2f3, b2f, acc2[3], 0, 0, 0);
    }
    // ---- store + residual; keep ef_out value in acc2 for the fused dot ----
    #pragma unroll
    for (int mt = 0; mt < 4; ++mt) {
        int row0 = mt * 16 + quad * 4;
        #pragma unroll
        for (int r = 0; r < 4; ++r) {
            int ge = e0 + row0 + r;
            float v = 0.f;
            if (ge < E) {
                size_t o = (size_t)ge * D + col2;
                v = acc2[mt][r] + ef_in[o];
                ef_out[o] = v;
            }
            acc2[mt][r] = v;
        }
    }

    // ---- fused next-layer alpha dot: p[e][h] = sum_d ef_out[e][d] * weffN[d*4+h]
    if (palpha) {
        __syncthreads();                       // all GEMM2 A1 reads complete
        float* A1f = (float*)A1;               // [64][68] fp32 (17.4KB <= 25.6KB)
        #pragma unroll
        for (int mt = 0; mt < 4; ++mt) {
            #pragma unroll
            for (int r = 0; r < 4; ++r)
                A1f[(mt * 16 + quad * 4 + r) * 68 + col2] = acc2[mt][r];
        }
        float* wst = &ps[0][0];                // 256 floats, ps/pq dead now
        if (tid < 64) *(float4*)&wst[tid * 4] = *(const float4*)&weffN[tid * 4];
        __syncthreads();
        int e = tid >> 2, h = tid & 3;
        int ge = e0 + e;
        float p = 0.f;
        #pragma unroll
        for (int d = 0; d < 64; ++d)
            p = fmaf(A1f[e * 68 + d], wst[d * 4 + h], p);
        if (ge < E) palpha[(size_t)ge * 4 + h] = p;
    }
}

extern "C" void kernel_launch(void* const* d_in, const int* in_sizes, int n_in,
                              void* d_out, int out_size, void* d_ws, size_t ws_size,
                              hipStream_t stream) {
    const float* nf_in0   = (const float*)d_in[0];
    const float* ef_in0   = (const float*)d_in[1];
    const int*   eidx     = (const int*)d_in[2];
    const float* W_lin    = (const float*)d_in[3];
    const float* W_edge   = (const float*)d_in[4];
    const float* att_src  = (const float*)d_in[5];
    const float* att_dst  = (const float*)d_in[6];
    const float* att_edge = (const float*)d_in[7];
    const float* biasc    = (const float*)d_in[8];
    const float* ln_g     = (const float*)d_in[9];
    const float* ln_b     = (const float*)d_in[10];
    const float* eW1      = (const float*)d_in[11];
    const float* eb1      = (const float*)d_in[12];
    const float* eln_g    = (const float*)d_in[13];
    const float* eln_b    = (const float*)d_in[14];
    const float* eW2      = (const float*)d_in[15];
    const float* eb2      = (const float*)d_in[16];

    int N = in_sizes[0] / D;
    int E = in_sizes[1] / D;
    const int* srcp = eidx;
    const int* dstp = eidx + E;

    float* ws        = (float*)d_ws;
    float* x         = ws;                               // N*256
    float* alpha_csr = x + (size_t)N * HC;               // E*4 (16B aligned)
    float* a_src     = alpha_csr + (size_t)E * H;        // N*4
    float* a_dst     = a_src + (size_t)N * H;            // N*4
    float* nf_ln     = a_dst + (size_t)N * H;            // N*64
    float* weff      = nf_ln + (size_t)N * D;            // L*256
    float* w_asd     = weff + NLAYERS * HC;              // L*512
    u16*   W1T       = (u16*)(w_asd + NLAYERS * 512);    // L*192*192 bf16
    u16*   W2T       = W1T + (size_t)NLAYERS * D3 * D3;  // L*64*192 bf16
    u16*   WLh       = W2T + (size_t)NLAYERS * D3 * D;   // L*256*64 bf16 (W_lin^T hi)
    u16*   WLl       = WLh + (size_t)NLAYERS * HC * D;   // L*256*64 bf16 (W_lin^T lo)
    int*   rowptr    = (int*)(WLl + (size_t)NLAYERS * HC * D); // N+1
    int*   head      = rowptr + (N + 1);                 // N
    int*   csrpos    = head + N;                         // E
    int*   perm_src  = csrpos + (size_t)E;               // E
    float* palpha    = (float*)(perm_src + (size_t)E);   // E*4

    float* out_nf = (float*)d_out;
    float* out_ef = out_nf + (size_t)N * D;

    // ---- once per launch: weights + CSR ----
    {
        int total = NLAYERS * D3 * D3 + NLAYERS * D3 * D;
        k_cvtw<<<(total + 255) / 256, 256, 0, stream>>>(eW1, eW2, W1T, W2T);
        k_cvtwl<<<(NLAYERS * HC * D + 255) / 256, 256, 0, stream>>>(W_lin, WLh, WLl);
        k_weffs<<<NLAYERS, 256, 0, stream>>>(W_edge, att_edge, W_lin, att_src, att_dst,
                                             weff, w_asd);
        hipMemsetAsync(head, 0, (size_t)N * sizeof(int), stream);  // head used as deg first
        k_hist<<<(E + 255) / 256, 256, 0, stream>>>(dstp, head, E);
        k_scan<<<1, 1024, 0, stream>>>(head, rowptr, head, N, E);  // deg in, head out
        k_scatter<<<(E + 255) / 256, 256, 0, stream>>>(srcp, dstp, head, csrpos, perm_src, E);
    }

    for (int l = 0; l < NLAYERS; ++l) {
        const float* nf_cur = (l == 0) ? nf_in0 : nf_ln;
        const float* ef_cur = (l == 0) ? ef_in0 : out_ef;
        int relu_in = (l > 0) ? 1 : 0;

        k_nodeproj_mfma<<<(N + 31) / 32, 256, 0, stream>>>(
            nf_cur, WLh + (size_t)l * HC * D, WLl + (size_t)l * HC * D,
            w_asd + (size_t)l * 512, x, a_src, a_dst, N, relu_in);
        if (l == 0) {
            k_alpha<<<(E + 15) / 16, 256, 0, stream>>>(ef_cur, weff + (size_t)l * HC,
                                                       srcp, dstp, a_src, a_dst,
                                                       csrpos, alpha_csr, E);
        } else {
            k_alpha_lite<<<(E * 4 + 255) / 256, 256, 0, stream>>>(palpha, srcp, dstp,
                                                                  a_src, a_dst,
                                                                  csrpos, alpha_csr, E);
        }
        k_gat<<<(N + 3) / 4, 256, 0, stream>>>(x, alpha_csr, rowptr, perm_src,
                                               biasc + l * D, ln_g + l * D, ln_b + l * D,
                                               nf_ln, (l == NLAYERS - 1) ? out_nf : nullptr, N);
        const float* weffN = (l < NLAYERS - 1) ? (weff + (size_t)(l + 1) * HC) : nullptr;
        float* pout = (l < NLAYERS - 1) ? palpha : nullptr;
        k_edgemlp_mfma<<<(E + 63) / 64, 256, 0, stream>>>(nf_ln, ef_cur, srcp, dstp,
                                                          W1T + (size_t)l * D3 * D3, eb1 + l * D3,
                                                          eln_g + l * D3, eln_b + l * D3,
                                                          W2T + (size_t)l * D3 * D, eb2 + l * D,
                                                          out_ef, weffN, pout, E);
    }
}